// Round 5
// baseline (8456.869 us; speedup 1.0000x reference)
//
#include <hip/hip_runtime.h>
#include <math.h>

#define NEG 0.2f

// ---------------- Layer-1 node transform: h1 = x@W1, alpha_s/d ----------------
__global__ __launch_bounds__(256) void k1_node(const float* __restrict__ x,
    const float* __restrict__ W1, const float* __restrict__ a1s, const float* __restrict__ a1d,
    float* __restrict__ h1, float* __restrict__ as1, float* __restrict__ ad1, int n)
{
    __shared__ float wt[8 * 128];   // W1 transposed: wt[k][i]
    __shared__ float av[16];        // a1_src | a1_dst
    for (int i = threadIdx.x; i < 1024; i += 256) {
        int r = i >> 3, k = i & 7;  // W1[r][k] row-major [128,8]
        wt[k * 128 + r] = W1[i];
    }
    if (threadIdx.x < 8)        av[threadIdx.x] = a1s[threadIdx.x];
    else if (threadIdx.x < 16)  av[threadIdx.x] = a1d[threadIdx.x - 8];
    __syncthreads();

    int lane = threadIdx.x & 31;
    int node = blockIdx.x * 8 + (threadIdx.x >> 5);
    if (node >= n) return;

    float4 xv = ((const float4*)(x + (size_t)node * 128))[lane];
    float p[8];
#pragma unroll
    for (int k = 0; k < 8; ++k) {
        float4 wv = ((const float4*)(wt + k * 128))[lane];  // contiguous: conflict-free
        p[k] = xv.x * wv.x + xv.y * wv.y + xv.z * wv.z + xv.w * wv.w;
    }
#pragma unroll
    for (int off = 16; off; off >>= 1)
#pragma unroll
        for (int k = 0; k < 8; ++k) p[k] += __shfl_down(p[k], off, 32);

    if (lane == 0) {
        float s = 0.f, d = 0.f;
#pragma unroll
        for (int k = 0; k < 8; ++k) {
            h1[(size_t)node * 8 + k] = p[k];
            s += p[k] * av[k];
            d += p[k] * av[8 + k];
        }
        as1[node] = s;
        ad1[node] = d;
    }
}

// ---------------- Edge scatter pass (both layers, F = feature width) ----------------
template <int F>
__global__ __launch_bounds__(256) void k_edge(const int* __restrict__ src, const int* __restrict__ dst,
    const float* __restrict__ as, const float* __restrict__ ad, const float* __restrict__ feat,
    float* __restrict__ denom, float* __restrict__ acc, int E)
{
    int e = blockIdx.x * 256 + threadIdx.x;
    if (e >= E) return;
    int s = src[e], d = dst[e];
    float t = as[s] + ad[d];
    float w = __expf(t > 0.f ? t : NEG * t);  // softmax max-shift skipped: |t| <= ~8, exact same ratio
    atomicAdd(denom + d, w);
    const float* fs = feat + (size_t)s * F;
    float* ac = acc + (size_t)d * F;
#pragma unroll
    for (int k = 0; k < F; ++k) atomicAdd(ac + k, w * fs[k]);
}

// ---------------- Layer-1 finalize + layer-2 node transform ----------------
__global__ __launch_bounds__(256) void k3_node(const float* __restrict__ denom1,
    const float* __restrict__ acc1, const float* __restrict__ b1,
    const float* __restrict__ W2, const float* __restrict__ a2s, const float* __restrict__ a2d,
    float* __restrict__ g, float* __restrict__ as2, float* __restrict__ ad2, int n)
{
    __shared__ float w2[128];  // W2 [8,16] row-major
    __shared__ float aa[32];   // a2_src | a2_dst
    __shared__ float bb[8];    // b1
    if (threadIdx.x < 128) w2[threadIdx.x] = W2[threadIdx.x];
    if (threadIdx.x >= 128 && threadIdx.x < 144) aa[threadIdx.x - 128] = a2s[threadIdx.x - 128];
    if (threadIdx.x >= 144 && threadIdx.x < 160) aa[16 + threadIdx.x - 144] = a2d[threadIdx.x - 144];
    if (threadIdx.x >= 160 && threadIdx.x < 168) bb[threadIdx.x - 160] = b1[threadIdx.x - 160];
    __syncthreads();

    int node = blockIdx.x * 256 + threadIdx.x;
    if (node >= n) return;
    float dn = denom1[node];
    float inv = dn > 0.f ? 1.f / dn : 0.f;  // isolated node -> 0 (matches ref: empty segment sum)
    float h[8];
#pragma unroll
    for (int k = 0; k < 8; ++k) {
        float v = acc1[(size_t)node * 8 + k] * inv + bb[k];
        h[k] = v > 0.f ? v : 0.f;  // ReLU between layers
    }
    float s = 0.f, dd = 0.f;
#pragma unroll
    for (int c = 0; c < 16; ++c) {
        float gv = 0.f;
#pragma unroll
        for (int k = 0; k < 8; ++k) gv += h[k] * w2[k * 16 + c];
        g[(size_t)node * 16 + c] = gv;
        s += gv * aa[c];
        dd += gv * aa[16 + c];
    }
    as2[node] = s;
    ad2[node] = dd;
}

// ---------------- Layer-2 finalize + log_softmax ----------------
__global__ __launch_bounds__(256) void k5_final(const float* __restrict__ denom2,
    const float* __restrict__ acc2, const float* __restrict__ b2, float* __restrict__ out, int n)
{
    __shared__ float bb[16];
    if (threadIdx.x < 16) bb[threadIdx.x] = b2[threadIdx.x];
    __syncthreads();

    int node = blockIdx.x * 256 + threadIdx.x;
    if (node >= n) return;
    float dn = denom2[node];
    float inv = dn > 0.f ? 1.f / dn : 0.f;
    float o[16];
    float m = -1e30f;
#pragma unroll
    for (int c = 0; c < 16; ++c) {
        o[c] = acc2[(size_t)node * 16 + c] * inv + bb[c];
        m = fmaxf(m, o[c]);
    }
    float se = 0.f;
#pragma unroll
    for (int c = 0; c < 16; ++c) {
        o[c] -= m;
        se += __expf(o[c]);
    }
    float l = __logf(se);
#pragma unroll
    for (int c = 0; c < 16; ++c) out[(size_t)node * 16 + c] = o[c] - l;
}

extern "C" void kernel_launch(void* const* d_in, const int* in_sizes, int n_in,
                              void* d_out, int out_size, void* d_ws, size_t ws_size,
                              hipStream_t stream)
{
    const float* x    = (const float*)d_in[0];
    const int*   eidx = (const int*)d_in[1];
    const float* W1   = (const float*)d_in[2];
    const float* a1s  = (const float*)d_in[3];
    const float* a1d  = (const float*)d_in[4];
    const float* b1   = (const float*)d_in[5];
    const float* W2   = (const float*)d_in[6];
    const float* a2s  = (const float*)d_in[7];
    const float* a2d  = (const float*)d_in[8];
    const float* b2   = (const float*)d_in[9];
    float* out = (float*)d_out;

    const int n = in_sizes[0] / 128;
    const int E = in_sizes[1] / 2;
    const int* src = eidx;
    const int* dst = eidx + E;

    // Workspace layout (floats). First 26n floats are accumulators -> zeroed each call.
    float* ws    = (float*)d_ws;
    float* denom1 = ws;                    // [n]
    float* acc1   = ws + (size_t)n;        // [8n]
    float* denom2 = ws + (size_t)9 * n;    // [n]
    float* acc2   = ws + (size_t)10 * n;   // [16n]
    float* h1     = ws + (size_t)26 * n;   // [8n]
    float* as1    = ws + (size_t)34 * n;   // [n]
    float* ad1    = ws + (size_t)35 * n;   // [n]
    float* g      = ws + (size_t)36 * n;   // [16n]
    float* as2    = ws + (size_t)52 * n;   // [n]
    float* ad2    = ws + (size_t)53 * n;   // [n]

    hipMemsetAsync(ws, 0, (size_t)26 * n * sizeof(float), stream);

    k1_node<<<(n + 7) / 8, 256, 0, stream>>>(x, W1, a1s, a1d, h1, as1, ad1, n);
    k_edge<8><<<(E + 255) / 256, 256, 0, stream>>>(src, dst, as1, ad1, h1, denom1, acc1, E);
    k3_node<<<(n + 255) / 256, 256, 0, stream>>>(denom1, acc1, b1, W2, a2s, a2d, g, as2, ad2, n);
    k_edge<16><<<(E + 255) / 256, 256, 0, stream>>>(src, dst, as2, ad2, g, denom2, acc2, E);
    k5_final<<<(n + 255) / 256, 256, 0, stream>>>(denom2, acc2, b2, out, n);
}

// Round 6
// 1237.975 us; speedup vs baseline: 6.8312x; 6.8312x over previous
//
#include <hip/hip_runtime.h>
#include <math.h>

#define NEG 0.2f

// ============================ shared node kernels ============================

// Layer-1 node transform: h1 = x@W1, alpha_s/d
__global__ __launch_bounds__(256) void k1_node(const float* __restrict__ x,
    const float* __restrict__ W1, const float* __restrict__ a1s, const float* __restrict__ a1d,
    float* __restrict__ h1, float* __restrict__ as1, float* __restrict__ ad1, int n)
{
    __shared__ float wt[8 * 128];   // W1 transposed: wt[k][i]
    __shared__ float av[16];        // a1_src | a1_dst
    for (int i = threadIdx.x; i < 1024; i += 256) {
        int r = i >> 3, k = i & 7;  // W1[r][k] row-major [128,8]
        wt[k * 128 + r] = W1[i];
    }
    if (threadIdx.x < 8)        av[threadIdx.x] = a1s[threadIdx.x];
    else if (threadIdx.x < 16)  av[threadIdx.x] = a1d[threadIdx.x - 8];
    __syncthreads();

    int lane = threadIdx.x & 31;
    int node = blockIdx.x * 8 + (threadIdx.x >> 5);
    if (node >= n) return;

    float4 xv = ((const float4*)(x + (size_t)node * 128))[lane];
    float p[8];
#pragma unroll
    for (int k = 0; k < 8; ++k) {
        float4 wv = ((const float4*)(wt + k * 128))[lane];
        p[k] = xv.x * wv.x + xv.y * wv.y + xv.z * wv.z + xv.w * wv.w;
    }
#pragma unroll
    for (int off = 16; off; off >>= 1)
#pragma unroll
        for (int k = 0; k < 8; ++k) p[k] += __shfl_down(p[k], off, 32);

    if (lane == 0) {
        float s = 0.f, d = 0.f;
#pragma unroll
        for (int k = 0; k < 8; ++k) {
            h1[(size_t)node * 8 + k] = p[k];
            s += p[k] * av[k];
            d += p[k] * av[8 + k];
        }
        as1[node] = s;
        ad1[node] = d;
    }
}

// Layer-2 node transform from already-finalized h': g = h'@W2, alphas
__global__ __launch_bounds__(256) void k3b_node(const float* __restrict__ h1p,
    const float* __restrict__ W2, const float* __restrict__ a2s, const float* __restrict__ a2d,
    float* __restrict__ g, float* __restrict__ as2, float* __restrict__ ad2, int n)
{
    __shared__ float w2[128];  // W2 [8,16] row-major
    __shared__ float aa[32];   // a2_src | a2_dst
    if (threadIdx.x < 128) w2[threadIdx.x] = W2[threadIdx.x];
    if (threadIdx.x >= 128 && threadIdx.x < 144) aa[threadIdx.x - 128] = a2s[threadIdx.x - 128];
    if (threadIdx.x >= 144 && threadIdx.x < 160) aa[16 + threadIdx.x - 144] = a2d[threadIdx.x - 144];
    __syncthreads();

    int node = blockIdx.x * 256 + threadIdx.x;
    if (node >= n) return;
    float4 h0 = ((const float4*)(h1p + (size_t)node * 8))[0];
    float4 h4 = ((const float4*)(h1p + (size_t)node * 8))[1];
    float h[8] = {h0.x, h0.y, h0.z, h0.w, h4.x, h4.y, h4.z, h4.w};
    float s = 0.f, dd = 0.f;
#pragma unroll
    for (int c = 0; c < 16; ++c) {
        float gv = 0.f;
#pragma unroll
        for (int k = 0; k < 8; ++k) gv += h[k] * w2[k * 16 + c];
        g[(size_t)node * 16 + c] = gv;
        s += gv * aa[c];
        dd += gv * aa[16 + c];
    }
    as2[node] = s;
    ad2[node] = dd;
}

// ============================ CSR build ============================

__global__ __launch_bounds__(256) void k_hist(const int* __restrict__ dst, int* __restrict__ deg, int E)
{
    int e = blockIdx.x * 256 + threadIdx.x;
    if (e < E) atomicAdd(deg + dst[e], 1);
}

// single-block exclusive scan of deg[n] -> row_ptr[n] (+ row_ptr[n]=E)
__global__ __launch_bounds__(1024) void k_scan(const int* __restrict__ deg, int* __restrict__ row_ptr,
                                               int n, int E)
{
    const int T = 1024;
    int tid = threadIdx.x;
    int chunk = (n + T - 1) / T;
    int base = tid * chunk;
    int s = 0;
    for (int j = 0; j < chunk; ++j) {
        int idx = base + j;
        if (idx < n) s += deg[idx];
    }
    int lane = tid & 63, w = tid >> 6;
    int v = s;
#pragma unroll
    for (int off = 1; off < 64; off <<= 1) {
        int t = __shfl_up(v, off, 64);
        if (lane >= off) v += t;
    }
    __shared__ int wsum[16];
    if (lane == 63) wsum[w] = v;
    __syncthreads();
    if (tid == 0) {
        int a = 0;
#pragma unroll
        for (int i = 0; i < 16; ++i) { int t = wsum[i]; wsum[i] = a; a += t; }
    }
    __syncthreads();
    int run = v - s + wsum[w];  // exclusive prefix for this thread's chunk
    for (int j = 0; j < chunk; ++j) {
        int idx = base + j;
        if (idx < n) { row_ptr[idx] = run; run += deg[idx]; }
    }
    if (tid == 0) row_ptr[n] = E;
}

__global__ __launch_bounds__(256) void k_scatter(const int* __restrict__ src, const int* __restrict__ dst,
    int* __restrict__ cursor, int* __restrict__ colsrc, int E)
{
    int e = blockIdx.x * 256 + threadIdx.x;
    if (e >= E) return;
    int d = dst[e];
    int pos = atomicAdd(cursor + d, 1);
    colsrc[pos] = src[e];
}

// ============================ atomic-free gather ============================
// One wave per destination node. Lanes sweep the node's contiguous CSR run,
// butterfly-reduce (F+1) partial sums, fused epilogue.
// FINAL=false: out = relu(acc/denom + bias)   (layer 1 -> h')
// FINAL=true : out = log_softmax(acc/denom + bias)  (layer 2 -> d_out)
template <int F, bool FINAL>
__global__ __launch_bounds__(256) void k_gather(const int* __restrict__ row_ptr,
    const int* __restrict__ colsrc, const float* __restrict__ as, const float* __restrict__ ad,
    const float* __restrict__ feat, const float* __restrict__ bias, float* __restrict__ outp, int n)
{
    int node = (blockIdx.x * 256 + threadIdx.x) >> 6;  // global wave id
    int lane = threadIdx.x & 63;
    if (node >= n) return;
    int start = row_ptr[node], end = row_ptr[node + 1];
    float adn = ad[node];
    float wsum = 0.f;
    float acc[F];
#pragma unroll
    for (int k = 0; k < F; ++k) acc[k] = 0.f;

    for (int i = start + lane; i < end; i += 64) {
        int s = colsrc[i];
        float t = as[s] + adn;
        float w = __expf(t > 0.f ? t : NEG * t);  // max-shift skipped: |t| small, exact ratio
        wsum += w;
        const float4* fs4 = (const float4*)(feat + (size_t)s * F);
#pragma unroll
        for (int q = 0; q < F / 4; ++q) {
            float4 fv = fs4[q];
            acc[4 * q + 0] += w * fv.x;
            acc[4 * q + 1] += w * fv.y;
            acc[4 * q + 2] += w * fv.z;
            acc[4 * q + 3] += w * fv.w;
        }
    }
#pragma unroll
    for (int off = 32; off; off >>= 1) {
        wsum += __shfl_xor(wsum, off, 64);
#pragma unroll
        for (int k = 0; k < F; ++k) acc[k] += __shfl_xor(acc[k], off, 64);
    }
    float inv = wsum > 0.f ? 1.f / wsum : 0.f;  // isolated node -> bias only (matches ref)

    if (FINAL) {
        float o[F], m = -1e30f;
#pragma unroll
        for (int c = 0; c < F; ++c) {
            o[c] = acc[c] * inv + bias[c];
            m = fmaxf(m, o[c]);
        }
        float se = 0.f;
#pragma unroll
        for (int c = 0; c < F; ++c) se += __expf(o[c] - m);
        float l = m + __logf(se);
        if (lane < F) outp[(size_t)node * F + lane] = o[lane] - l;
    } else {
        if (lane < F) {
            float v = acc[lane] * inv + bias[lane];
            outp[(size_t)node * F + lane] = v > 0.f ? v : 0.f;
        }
    }
}

// ============================ fallback (atomic) path ============================

template <int F>
__global__ __launch_bounds__(256) void k_edge(const int* __restrict__ src, const int* __restrict__ dst,
    const float* __restrict__ as, const float* __restrict__ ad, const float* __restrict__ feat,
    float* __restrict__ denom, float* __restrict__ acc, int E)
{
    int e = blockIdx.x * 256 + threadIdx.x;
    if (e >= E) return;
    int s = src[e], d = dst[e];
    float t = as[s] + ad[d];
    float w = __expf(t > 0.f ? t : NEG * t);
    atomicAdd(denom + d, w);
    const float* fs = feat + (size_t)s * F;
    float* ac = acc + (size_t)d * F;
#pragma unroll
    for (int k = 0; k < F; ++k) atomicAdd(ac + k, w * fs[k]);
}

__global__ __launch_bounds__(256) void k3_node(const float* __restrict__ denom1,
    const float* __restrict__ acc1, const float* __restrict__ b1,
    const float* __restrict__ W2, const float* __restrict__ a2s, const float* __restrict__ a2d,
    float* __restrict__ g, float* __restrict__ as2, float* __restrict__ ad2, int n)
{
    __shared__ float w2[128];
    __shared__ float aa[32];
    __shared__ float bb[8];
    if (threadIdx.x < 128) w2[threadIdx.x] = W2[threadIdx.x];
    if (threadIdx.x >= 128 && threadIdx.x < 144) aa[threadIdx.x - 128] = a2s[threadIdx.x - 128];
    if (threadIdx.x >= 144 && threadIdx.x < 160) aa[16 + threadIdx.x - 144] = a2d[threadIdx.x - 144];
    if (threadIdx.x >= 160 && threadIdx.x < 168) bb[threadIdx.x - 160] = b1[threadIdx.x - 160];
    __syncthreads();

    int node = blockIdx.x * 256 + threadIdx.x;
    if (node >= n) return;
    float dn = denom1[node];
    float inv = dn > 0.f ? 1.f / dn : 0.f;
    float h[8];
#pragma unroll
    for (int k = 0; k < 8; ++k) {
        float v = acc1[(size_t)node * 8 + k] * inv + bb[k];
        h[k] = v > 0.f ? v : 0.f;
    }
    float s = 0.f, dd = 0.f;
#pragma unroll
    for (int c = 0; c < 16; ++c) {
        float gv = 0.f;
#pragma unroll
        for (int k = 0; k < 8; ++k) gv += h[k] * w2[k * 16 + c];
        g[(size_t)node * 16 + c] = gv;
        s += gv * aa[c];
        dd += gv * aa[16 + c];
    }
    as2[node] = s;
    ad2[node] = dd;
}

__global__ __launch_bounds__(256) void k5_final(const float* __restrict__ denom2,
    const float* __restrict__ acc2, const float* __restrict__ b2, float* __restrict__ out, int n)
{
    __shared__ float bb[16];
    if (threadIdx.x < 16) bb[threadIdx.x] = b2[threadIdx.x];
    __syncthreads();

    int node = blockIdx.x * 256 + threadIdx.x;
    if (node >= n) return;
    float dn = denom2[node];
    float inv = dn > 0.f ? 1.f / dn : 0.f;
    float o[16];
    float m = -1e30f;
#pragma unroll
    for (int c = 0; c < 16; ++c) {
        o[c] = acc2[(size_t)node * 16 + c] * inv + bb[c];
        m = fmaxf(m, o[c]);
    }
    float se = 0.f;
#pragma unroll
    for (int c = 0; c < 16; ++c) {
        o[c] -= m;
        se += __expf(o[c]);
    }
    float l = __logf(se);
#pragma unroll
    for (int c = 0; c < 16; ++c) out[(size_t)node * 16 + c] = o[c] - l;
}

// ============================ launch ============================

extern "C" void kernel_launch(void* const* d_in, const int* in_sizes, int n_in,
                              void* d_out, int out_size, void* d_ws, size_t ws_size,
                              hipStream_t stream)
{
    const float* x    = (const float*)d_in[0];
    const int*   eidx = (const int*)d_in[1];
    const float* W1   = (const float*)d_in[2];
    const float* a1s  = (const float*)d_in[3];
    const float* a1d  = (const float*)d_in[4];
    const float* b1   = (const float*)d_in[5];
    const float* W2   = (const float*)d_in[6];
    const float* a2s  = (const float*)d_in[7];
    const float* a2d  = (const float*)d_in[8];
    const float* b2   = (const float*)d_in[9];
    float* out = (float*)d_out;

    const int n = in_sizes[0] / 128;
    const int E = in_sizes[1] / 2;
    const int* src = eidx;
    const int* dst = eidx + E;

    // ---- CSR-path workspace layout (all chunks 64B-aligned) ----
    // ints: colsrc[E] | deg[n] | cursor[n] | row_ptr[n+16]
    // floats: h1[8n] | h1p[8n] | g[16n] | as1[n] | ad1[n] | as2[n] | ad2[n]
    size_t int_elems = (size_t)E + n + n + (n + 16);
    size_t flt_elems = (size_t)36 * n;
    size_t needed = 4 * (int_elems + flt_elems);

    if (ws_size >= needed) {
        char* p = (char*)d_ws;
        int* colsrc  = (int*)p;               p += (size_t)E * 4;
        int* deg     = (int*)p;               p += (size_t)n * 4;
        int* cursor  = (int*)p;               p += (size_t)n * 4;
        int* row_ptr = (int*)p;               p += (size_t)(n + 16) * 4;
        float* h1    = (float*)p;             p += (size_t)8 * n * 4;
        float* h1p   = (float*)p;             p += (size_t)8 * n * 4;
        float* g     = (float*)p;             p += (size_t)16 * n * 4;
        float* as1   = (float*)p;             p += (size_t)n * 4;
        float* ad1   = (float*)p;             p += (size_t)n * 4;
        float* as2   = (float*)p;             p += (size_t)n * 4;
        float* ad2   = (float*)p;

        hipMemsetAsync(deg, 0, (size_t)n * 4, stream);

        // node transform (independent of CSR build)
        k1_node<<<(n + 7) / 8, 256, 0, stream>>>(x, W1, a1s, a1d, h1, as1, ad1, n);

        // CSR build: histogram -> scan -> scatter
        k_hist<<<(E + 255) / 256, 256, 0, stream>>>(dst, deg, E);
        k_scan<<<1, 1024, 0, stream>>>(deg, row_ptr, n, E);
        hipMemcpyAsync(cursor, row_ptr, (size_t)n * 4, hipMemcpyDeviceToDevice, stream);
        k_scatter<<<(E + 255) / 256, 256, 0, stream>>>(src, dst, cursor, colsrc, E);

        const int gblocks = (n * 64 + 255) / 256;
        // layer 1: gather + normalize + bias + relu -> h1p
        k_gather<8, false><<<gblocks, 256, 0, stream>>>(row_ptr, colsrc, as1, ad1, h1, b1, h1p, n);
        // layer 2 node transform
        k3b_node<<<(n + 255) / 256, 256, 0, stream>>>(h1p, W2, a2s, a2d, g, as2, ad2, n);
        // layer 2: gather + normalize + bias + log_softmax -> out
        k_gather<16, true><<<gblocks, 256, 0, stream>>>(row_ptr, colsrc, as2, ad2, g, b2, out, n);
    } else {
        // ---- fallback: original atomic-scatter path ----
        float* ws     = (float*)d_ws;
        float* denom1 = ws;
        float* acc1   = ws + (size_t)n;
        float* denom2 = ws + (size_t)9 * n;
        float* acc2   = ws + (size_t)10 * n;
        float* h1     = ws + (size_t)26 * n;
        float* as1    = ws + (size_t)34 * n;
        float* ad1    = ws + (size_t)35 * n;
        float* g      = ws + (size_t)36 * n;
        float* as2    = ws + (size_t)52 * n;
        float* ad2    = ws + (size_t)53 * n;

        hipMemsetAsync(ws, 0, (size_t)26 * n * sizeof(float), stream);
        k1_node<<<(n + 7) / 8, 256, 0, stream>>>(x, W1, a1s, a1d, h1, as1, ad1, n);
        k_edge<8><<<(E + 255) / 256, 256, 0, stream>>>(src, dst, as1, ad1, h1, denom1, acc1, E);
        k3_node<<<(n + 255) / 256, 256, 0, stream>>>(denom1, acc1, b1, W2, a2s, a2d, g, as2, ad2, n);
        k_edge<16><<<(E + 255) / 256, 256, 0, stream>>>(src, dst, as2, ad2, g, denom2, acc2, E);
        k5_final<<<(n + 255) / 256, 256, 0, stream>>>(denom2, acc2, b2, out, n);
    }
}

// Round 7
// 376.874 us; speedup vs baseline: 22.4395x; 3.2849x over previous
//
#include <hip/hip_runtime.h>
#include <math.h>
#include <stdint.h>

#define NEG 0.2f
#define CSHIFT 8
#define MAXNB 512          // supports n <= 131072 (17-bit src pack)
#define P1_CHUNK 16384

// ============================ shared node kernels ============================

__global__ __launch_bounds__(256) void k1_node(const float* __restrict__ x,
    const float* __restrict__ W1, const float* __restrict__ a1s, const float* __restrict__ a1d,
    float* __restrict__ h1, float* __restrict__ as1, float* __restrict__ ad1, int n)
{
    __shared__ float wt[8 * 128];
    __shared__ float av[16];
    for (int i = threadIdx.x; i < 1024; i += 256) {
        int r = i >> 3, k = i & 7;
        wt[k * 128 + r] = W1[i];
    }
    if (threadIdx.x < 8)        av[threadIdx.x] = a1s[threadIdx.x];
    else if (threadIdx.x < 16)  av[threadIdx.x] = a1d[threadIdx.x - 8];
    __syncthreads();

    int lane = threadIdx.x & 31;
    int node = blockIdx.x * 8 + (threadIdx.x >> 5);
    if (node >= n) return;

    float4 xv = ((const float4*)(x + (size_t)node * 128))[lane];
    float p[8];
#pragma unroll
    for (int k = 0; k < 8; ++k) {
        float4 wv = ((const float4*)(wt + k * 128))[lane];
        p[k] = xv.x * wv.x + xv.y * wv.y + xv.z * wv.z + xv.w * wv.w;
    }
#pragma unroll
    for (int off = 16; off; off >>= 1)
#pragma unroll
        for (int k = 0; k < 8; ++k) p[k] += __shfl_down(p[k], off, 32);

    if (lane == 0) {
        float s = 0.f, d = 0.f;
#pragma unroll
        for (int k = 0; k < 8; ++k) {
            h1[(size_t)node * 8 + k] = p[k];
            s += p[k] * av[k];
            d += p[k] * av[8 + k];
        }
        as1[node] = s;
        ad1[node] = d;
    }
}

__global__ __launch_bounds__(256) void k3b_node(const float* __restrict__ h1p,
    const float* __restrict__ W2, const float* __restrict__ a2s, const float* __restrict__ a2d,
    float* __restrict__ g, float* __restrict__ as2, float* __restrict__ ad2, int n)
{
    __shared__ float w2[128];
    __shared__ float aa[32];
    if (threadIdx.x < 128) w2[threadIdx.x] = W2[threadIdx.x];
    if (threadIdx.x >= 128 && threadIdx.x < 144) aa[threadIdx.x - 128] = a2s[threadIdx.x - 128];
    if (threadIdx.x >= 144 && threadIdx.x < 160) aa[16 + threadIdx.x - 144] = a2d[threadIdx.x - 144];
    __syncthreads();

    int node = blockIdx.x * 256 + threadIdx.x;
    if (node >= n) return;
    float4 h0 = ((const float4*)(h1p + (size_t)node * 8))[0];
    float4 h4 = ((const float4*)(h1p + (size_t)node * 8))[1];
    float h[8] = {h0.x, h0.y, h0.z, h0.w, h4.x, h4.y, h4.z, h4.w};
    float s = 0.f, dd = 0.f;
#pragma unroll
    for (int c = 0; c < 16; ++c) {
        float gv = 0.f;
#pragma unroll
        for (int k = 0; k < 8; ++k) gv += h[k] * w2[k * 16 + c];
        g[(size_t)node * 16 + c] = gv;
        s += gv * aa[c];
        dd += gv * aa[16 + c];
    }
    as2[node] = s;
    ad2[node] = dd;
}

// ============================ bucket-sort CSR build ============================

// pass 1a: coarse bucket histogram (LDS-staged, few global atomics)
__global__ __launch_bounds__(256) void p1a(const int* __restrict__ dst, int* __restrict__ gch,
                                           int E, int NB)
{
    __shared__ int h[MAXNB];
    for (int i = threadIdx.x; i < NB; i += 256) h[i] = 0;
    __syncthreads();
    int base = blockIdx.x * P1_CHUNK;
    int end = base + P1_CHUNK; if (end > E) end = E;
    for (int i = base + threadIdx.x; i < end; i += 256)
        atomicAdd(&h[dst[i] >> CSHIFT], 1);
    __syncthreads();
    for (int i = threadIdx.x; i < NB; i += 256)
        if (h[i]) atomicAdd(&gch[i], h[i]);
}

// coarse scan: single block (512 thr), NB <= 512
__global__ __launch_bounds__(512) void p_scan(const int* __restrict__ gch, int* __restrict__ cptr,
    int* __restrict__ cur, int* __restrict__ row_ptr, int NB, int n, int E)
{
    __shared__ int wsum[8];
    int tid = threadIdx.x;
    int v = tid < NB ? gch[tid] : 0;
    int lane = tid & 63, w = tid >> 6;
    int s = v;
#pragma unroll
    for (int off = 1; off < 64; off <<= 1) {
        int t = __shfl_up(s, off, 64);
        if (lane >= off) s += t;
    }
    if (lane == 63) wsum[w] = s;
    __syncthreads();
    if (tid == 0) { int a = 0; for (int i = 0; i < 8; ++i) { int t = wsum[i]; wsum[i] = a; a += t; } }
    __syncthreads();
    int excl = s - v + wsum[w];
    if (tid < NB) { cptr[tid] = excl; cur[tid] = excl; }
    if (tid == 0) { cptr[NB] = E; row_ptr[n] = E; }
}

// pass 1b: partition edges into coarse buckets, packed (fine<<17)|src
__global__ __launch_bounds__(256) void p1b(const int* __restrict__ src, const int* __restrict__ dst,
    int* __restrict__ cur, unsigned* __restrict__ stage, int E, int NB)
{
    __shared__ int h[MAXNB], bbase[MAXNB], ccur[MAXNB];
    for (int i = threadIdx.x; i < NB; i += 256) { h[i] = 0; ccur[i] = 0; }
    __syncthreads();
    int base = blockIdx.x * P1_CHUNK;
    int end = base + P1_CHUNK; if (end > E) end = E;
    for (int i = base + threadIdx.x; i < end; i += 256)
        atomicAdd(&h[dst[i] >> CSHIFT], 1);
    __syncthreads();
    for (int i = threadIdx.x; i < NB; i += 256)
        bbase[i] = h[i] ? atomicAdd(&cur[i], h[i]) : 0;
    __syncthreads();
    for (int i = base + threadIdx.x; i < end; i += 256) {
        int d = dst[i];
        int b = d >> CSHIFT;
        int off = atomicAdd(&ccur[b], 1);
        stage[bbase[b] + off] = ((unsigned)(d & ((1 << CSHIFT) - 1)) << 17) | (unsigned)src[i];
    }
}

// pass 2: per-bucket fine counting-sort -> colsrc + row_ptr
__global__ __launch_bounds__(256) void p2(const unsigned* __restrict__ stage,
    const int* __restrict__ cptr, int* __restrict__ colsrc, int* __restrict__ row_ptr, int n)
{
    int b = blockIdx.x;
    int nbase = b << CSHIFT;
    int NN = n - nbase; if (NN > 256) NN = 256;
    __shared__ int h[256], bps[256], cc[256];
    __shared__ int wsum[4];
    int tid = threadIdx.x;
    h[tid] = 0; cc[tid] = 0;
    __syncthreads();
    int s0 = cptr[b], s1 = cptr[b + 1];
    for (int i = s0 + tid; i < s1; i += 256)
        atomicAdd(&h[stage[i] >> 17], 1);
    __syncthreads();
    int v = h[tid];
    int lane = tid & 63, w = tid >> 6;
    int sc = v;
#pragma unroll
    for (int off = 1; off < 64; off <<= 1) {
        int t = __shfl_up(sc, off, 64);
        if (lane >= off) sc += t;
    }
    if (lane == 63) wsum[w] = sc;
    __syncthreads();
    if (tid == 0) { int a = 0; for (int i = 0; i < 4; ++i) { int t = wsum[i]; wsum[i] = a; a += t; } }
    __syncthreads();
    int excl = sc - v + wsum[w];
    bps[tid] = s0 + excl;
    if (tid < NN) row_ptr[nbase + tid] = s0 + excl;
    __syncthreads();
    for (int i = s0 + tid; i < s1; i += 256) {
        unsigned p = stage[i];
        int f = p >> 17;
        int off = atomicAdd(&cc[f], 1);
        colsrc[bps[f] + off] = (int)(p & 0x1FFFFu);
    }
}

// ============================ atomic-free gather ============================

template <int F, bool FINAL>
__global__ __launch_bounds__(256) void k_gather(const int* __restrict__ row_ptr,
    const int* __restrict__ colsrc, const float* __restrict__ as, const float* __restrict__ ad,
    const float* __restrict__ feat, const float* __restrict__ bias, float* __restrict__ outp, int n)
{
    int node = (blockIdx.x * 256 + threadIdx.x) >> 6;
    int lane = threadIdx.x & 63;
    if (node >= n) return;
    int start = row_ptr[node], end = row_ptr[node + 1];
    float adn = ad[node];
    float wsum = 0.f;
    float acc[F];
#pragma unroll
    for (int k = 0; k < F; ++k) acc[k] = 0.f;

    for (int i = start + lane; i < end; i += 64) {
        int s = colsrc[i];
        float t = as[s] + adn;
        float w = __expf(t > 0.f ? t : NEG * t);  // max-shift skipped: |t| small, exact ratio
        wsum += w;
        const float4* fs4 = (const float4*)(feat + (size_t)s * F);
#pragma unroll
        for (int q = 0; q < F / 4; ++q) {
            float4 fv = fs4[q];
            acc[4 * q + 0] += w * fv.x;
            acc[4 * q + 1] += w * fv.y;
            acc[4 * q + 2] += w * fv.z;
            acc[4 * q + 3] += w * fv.w;
        }
    }
#pragma unroll
    for (int off = 32; off; off >>= 1) {
        wsum += __shfl_xor(wsum, off, 64);
#pragma unroll
        for (int k = 0; k < F; ++k) acc[k] += __shfl_xor(acc[k], off, 64);
    }
    float inv = wsum > 0.f ? 1.f / wsum : 0.f;

    if (FINAL) {
        float o[F], m = -1e30f;
#pragma unroll
        for (int c = 0; c < F; ++c) {
            o[c] = acc[c] * inv + bias[c];
            m = fmaxf(m, o[c]);
        }
        float se = 0.f;
#pragma unroll
        for (int c = 0; c < F; ++c) se += __expf(o[c] - m);
        float l = m + __logf(se);
        if (lane < F) outp[(size_t)node * F + lane] = o[lane] - l;
    } else {
        if (lane < F) {
            float v = acc[lane] * inv + bias[lane];
            outp[(size_t)node * F + lane] = v > 0.f ? v : 0.f;
        }
    }
}

// ============================ legacy CSR build (fallback tier 1) ============================

__global__ __launch_bounds__(256) void k_hist(const int* __restrict__ dst, int* __restrict__ deg, int E)
{
    int e = blockIdx.x * 256 + threadIdx.x;
    if (e < E) atomicAdd(deg + dst[e], 1);
}

__global__ __launch_bounds__(1024) void k_scan(const int* __restrict__ deg, int* __restrict__ row_ptr,
                                               int n, int E)
{
    const int T = 1024;
    int tid = threadIdx.x;
    int chunk = (n + T - 1) / T;
    int base = tid * chunk;
    int s = 0;
    for (int j = 0; j < chunk; ++j) {
        int idx = base + j;
        if (idx < n) s += deg[idx];
    }
    int lane = tid & 63, w = tid >> 6;
    int v = s;
#pragma unroll
    for (int off = 1; off < 64; off <<= 1) {
        int t = __shfl_up(v, off, 64);
        if (lane >= off) v += t;
    }
    __shared__ int wsum[16];
    if (lane == 63) wsum[w] = v;
    __syncthreads();
    if (tid == 0) {
        int a = 0;
#pragma unroll
        for (int i = 0; i < 16; ++i) { int t = wsum[i]; wsum[i] = a; a += t; }
    }
    __syncthreads();
    int run = v - s + wsum[w];
    for (int j = 0; j < chunk; ++j) {
        int idx = base + j;
        if (idx < n) { row_ptr[idx] = run; run += deg[idx]; }
    }
    if (tid == 0) row_ptr[n] = E;
}

__global__ __launch_bounds__(256) void k_scatter(const int* __restrict__ src, const int* __restrict__ dst,
    int* __restrict__ cursor, int* __restrict__ colsrc, int E)
{
    int e = blockIdx.x * 256 + threadIdx.x;
    if (e >= E) return;
    int d = dst[e];
    int pos = atomicAdd(cursor + d, 1);
    colsrc[pos] = src[e];
}

// ============================ atomic path (fallback tier 2) ============================

template <int F>
__global__ __launch_bounds__(256) void k_edge(const int* __restrict__ src, const int* __restrict__ dst,
    const float* __restrict__ as, const float* __restrict__ ad, const float* __restrict__ feat,
    float* __restrict__ denom, float* __restrict__ acc, int E)
{
    int e = blockIdx.x * 256 + threadIdx.x;
    if (e >= E) return;
    int s = src[e], d = dst[e];
    float t = as[s] + ad[d];
    float w = __expf(t > 0.f ? t : NEG * t);
    atomicAdd(denom + d, w);
    const float* fs = feat + (size_t)s * F;
    float* ac = acc + (size_t)d * F;
#pragma unroll
    for (int k = 0; k < F; ++k) atomicAdd(ac + k, w * fs[k]);
}

__global__ __launch_bounds__(256) void k3_node(const float* __restrict__ denom1,
    const float* __restrict__ acc1, const float* __restrict__ b1,
    const float* __restrict__ W2, const float* __restrict__ a2s, const float* __restrict__ a2d,
    float* __restrict__ g, float* __restrict__ as2, float* __restrict__ ad2, int n)
{
    __shared__ float w2[128];
    __shared__ float aa[32];
    __shared__ float bb[8];
    if (threadIdx.x < 128) w2[threadIdx.x] = W2[threadIdx.x];
    if (threadIdx.x >= 128 && threadIdx.x < 144) aa[threadIdx.x - 128] = a2s[threadIdx.x - 128];
    if (threadIdx.x >= 144 && threadIdx.x < 160) aa[16 + threadIdx.x - 144] = a2d[threadIdx.x - 144];
    if (threadIdx.x >= 160 && threadIdx.x < 168) bb[threadIdx.x - 160] = b1[threadIdx.x - 160];
    __syncthreads();

    int node = blockIdx.x * 256 + threadIdx.x;
    if (node >= n) return;
    float dn = denom1[node];
    float inv = dn > 0.f ? 1.f / dn : 0.f;
    float h[8];
#pragma unroll
    for (int k = 0; k < 8; ++k) {
        float v = acc1[(size_t)node * 8 + k] * inv + bb[k];
        h[k] = v > 0.f ? v : 0.f;
    }
    float s = 0.f, dd = 0.f;
#pragma unroll
    for (int c = 0; c < 16; ++c) {
        float gv = 0.f;
#pragma unroll
        for (int k = 0; k < 8; ++k) gv += h[k] * w2[k * 16 + c];
        g[(size_t)node * 16 + c] = gv;
        s += gv * aa[c];
        dd += gv * aa[16 + c];
    }
    as2[node] = s;
    ad2[node] = dd;
}

__global__ __launch_bounds__(256) void k5_final(const float* __restrict__ denom2,
    const float* __restrict__ acc2, const float* __restrict__ b2, float* __restrict__ out, int n)
{
    __shared__ float bb[16];
    if (threadIdx.x < 16) bb[threadIdx.x] = b2[threadIdx.x];
    __syncthreads();

    int node = blockIdx.x * 256 + threadIdx.x;
    if (node >= n) return;
    float dn = denom2[node];
    float inv = dn > 0.f ? 1.f / dn : 0.f;
    float o[16];
    float m = -1e30f;
#pragma unroll
    for (int c = 0; c < 16; ++c) {
        o[c] = acc2[(size_t)node * 16 + c] * inv + bb[c];
        m = fmaxf(m, o[c]);
    }
    float se = 0.f;
#pragma unroll
    for (int c = 0; c < 16; ++c) {
        o[c] -= m;
        se += __expf(o[c]);
    }
    float l = __logf(se);
#pragma unroll
    for (int c = 0; c < 16; ++c) out[(size_t)node * 16 + c] = o[c] - l;
}

// ============================ launch ============================

static inline char* align256(char* p) {
    return (char*)(((uintptr_t)p + 255) & ~(uintptr_t)255);
}

extern "C" void kernel_launch(void* const* d_in, const int* in_sizes, int n_in,
                              void* d_out, int out_size, void* d_ws, size_t ws_size,
                              hipStream_t stream)
{
    const float* x    = (const float*)d_in[0];
    const int*   eidx = (const int*)d_in[1];
    const float* W1   = (const float*)d_in[2];
    const float* a1s  = (const float*)d_in[3];
    const float* a1d  = (const float*)d_in[4];
    const float* b1   = (const float*)d_in[5];
    const float* W2   = (const float*)d_in[6];
    const float* a2s  = (const float*)d_in[7];
    const float* a2d  = (const float*)d_in[8];
    const float* b2   = (const float*)d_in[9];
    float* out = (float*)d_out;

    const int n = in_sizes[0] / 128;
    const int E = in_sizes[1] / 2;
    const int* src = eidx;
    const int* dst = eidx + E;
    const int NB = (n + 255) >> CSHIFT;

    // ---- tier-0 layout: bucket-sort CSR ----
    // ints: stage[E] | colsrc[E] | gch[NB] | cptr[NB+1] | cur[NB] | row_ptr[n+1]
    // floats: h1[8n] | h1p[8n] | g[16n] | as1[n] | ad1[n] | as2[n] | ad2[n]
    {
        char* p = (char*)d_ws;
        char* p0 = p;
        unsigned* stage = (unsigned*)p;  p = align256(p + (size_t)E * 4);
        int* colsrc  = (int*)p;          p = align256(p + (size_t)E * 4);
        int* gch     = (int*)p;          p = align256(p + (size_t)NB * 4);
        int* cptr    = (int*)p;          p = align256(p + (size_t)(NB + 1) * 4);
        int* cur     = (int*)p;          p = align256(p + (size_t)NB * 4);
        int* row_ptr = (int*)p;          p = align256(p + (size_t)(n + 1) * 4);
        float* h1    = (float*)p;        p = align256(p + (size_t)8 * n * 4);
        float* h1p   = (float*)p;        p = align256(p + (size_t)8 * n * 4);
        float* g     = (float*)p;        p = align256(p + (size_t)16 * n * 4);
        float* as1   = (float*)p;        p = align256(p + (size_t)n * 4);
        float* ad1   = (float*)p;        p = align256(p + (size_t)n * 4);
        float* as2   = (float*)p;        p = align256(p + (size_t)n * 4);
        float* ad2   = (float*)p;        p = align256(p + (size_t)n * 4);
        size_t needed = (size_t)(p - p0);

        if (n <= 131072 && NB <= MAXNB && ws_size >= needed) {
            hipMemsetAsync(gch, 0, (size_t)NB * 4, stream);

            k1_node<<<(n + 7) / 8, 256, 0, stream>>>(x, W1, a1s, a1d, h1, as1, ad1, n);

            const int p1blocks = (E + P1_CHUNK - 1) / P1_CHUNK;
            p1a<<<p1blocks, 256, 0, stream>>>(dst, gch, E, NB);
            p_scan<<<1, 512, 0, stream>>>(gch, cptr, cur, row_ptr, NB, n, E);
            p1b<<<p1blocks, 256, 0, stream>>>(src, dst, cur, stage, E, NB);
            p2<<<NB, 256, 0, stream>>>(stage, cptr, colsrc, row_ptr, n);

            const int gblocks = (n * 64 + 255) / 256;
            k_gather<8, false><<<gblocks, 256, 0, stream>>>(row_ptr, colsrc, as1, ad1, h1, b1, h1p, n);
            k3b_node<<<(n + 255) / 256, 256, 0, stream>>>(h1p, W2, a2s, a2d, g, as2, ad2, n);
            k_gather<16, true><<<gblocks, 256, 0, stream>>>(row_ptr, colsrc, as2, ad2, g, b2, out, n);
            return;
        }
    }

    // ---- tier-1: legacy CSR (atomic scatter) ----
    {
        size_t int_elems = (size_t)E + n + n + (n + 16);
        size_t flt_elems = (size_t)36 * n;
        size_t needed = 4 * (int_elems + flt_elems);
        if (ws_size >= needed) {
            char* p = (char*)d_ws;
            int* colsrc  = (int*)p;               p += (size_t)E * 4;
            int* deg     = (int*)p;               p += (size_t)n * 4;
            int* cursor  = (int*)p;               p += (size_t)n * 4;
            int* row_ptr = (int*)p;               p += (size_t)(n + 16) * 4;
            float* h1    = (float*)p;             p += (size_t)8 * n * 4;
            float* h1p   = (float*)p;             p += (size_t)8 * n * 4;
            float* g     = (float*)p;             p += (size_t)16 * n * 4;
            float* as1   = (float*)p;             p += (size_t)n * 4;
            float* ad1   = (float*)p;             p += (size_t)n * 4;
            float* as2   = (float*)p;             p += (size_t)n * 4;
            float* ad2   = (float*)p;

            hipMemsetAsync(deg, 0, (size_t)n * 4, stream);
            k1_node<<<(n + 7) / 8, 256, 0, stream>>>(x, W1, a1s, a1d, h1, as1, ad1, n);
            k_hist<<<(E + 255) / 256, 256, 0, stream>>>(dst, deg, E);
            k_scan<<<1, 1024, 0, stream>>>(deg, row_ptr, n, E);
            hipMemcpyAsync(cursor, row_ptr, (size_t)n * 4, hipMemcpyDeviceToDevice, stream);
            k_scatter<<<(E + 255) / 256, 256, 0, stream>>>(src, dst, cursor, colsrc, E);

            const int gblocks = (n * 64 + 255) / 256;
            k_gather<8, false><<<gblocks, 256, 0, stream>>>(row_ptr, colsrc, as1, ad1, h1, b1, h1p, n);
            k3b_node<<<(n + 255) / 256, 256, 0, stream>>>(h1p, W2, a2s, a2d, g, as2, ad2, n);
            k_gather<16, true><<<gblocks, 256, 0, stream>>>(row_ptr, colsrc, as2, ad2, g, b2, out, n);
            return;
        }
    }

    // ---- tier-2: pure atomic path ----
    {
        float* ws     = (float*)d_ws;
        float* denom1 = ws;
        float* acc1   = ws + (size_t)n;
        float* denom2 = ws + (size_t)9 * n;
        float* acc2   = ws + (size_t)10 * n;
        float* h1     = ws + (size_t)26 * n;
        float* as1    = ws + (size_t)34 * n;
        float* ad1    = ws + (size_t)35 * n;
        float* g      = ws + (size_t)36 * n;
        float* as2    = ws + (size_t)52 * n;
        float* ad2    = ws + (size_t)53 * n;

        hipMemsetAsync(ws, 0, (size_t)26 * n * sizeof(float), stream);
        k1_node<<<(n + 7) / 8, 256, 0, stream>>>(x, W1, a1s, a1d, h1, as1, ad1, n);
        k_edge<8><<<(E + 255) / 256, 256, 0, stream>>>(src, dst, as1, ad1, h1, denom1, acc1, E);
        k3_node<<<(n + 255) / 256, 256, 0, stream>>>(denom1, acc1, b1, W2, a2s, a2d, g, as2, ad2, n);
        k_edge<16><<<(E + 255) / 256, 256, 0, stream>>>(src, dst, as2, ad2, g, denom2, acc2, E);
        k5_final<<<(n + 255) / 256, 256, 0, stream>>>(denom2, acc2, b2, out, n);
    }
}